// Round 9
// baseline (684.356 us; speedup 1.0000x reference)
//
#include <hip/hip_runtime.h>

// MoE top-2, E=8, T=8192, H=1024, I=2816. bf16 MFMA grouped-GEMM pipeline.
// R9: down split-K x2 (tail/occupancy fix: ~1024 -> ~2048 active blocks) with
//     weighted f32 atomicAdd epilogue straight into out (combine kernel removed).
//     Gateup R2-exact; fused GU transpose; vectorized router.

#define T_TOK 8192
#define H_DIM 1024
#define I_DIM 2816
#define NEXP  8
#define CAP   8192

typedef short bf16x8 __attribute__((ext_vector_type(8)));
typedef float f32x4  __attribute__((ext_vector_type(4)));

static __device__ __forceinline__ unsigned short f2bf(float f) {
  unsigned u = __float_as_uint(f);
  u = u + 0x7fffu + ((u >> 16) & 1u);   // RNE
  return (unsigned short)(u >> 16);
}

#define MFMA16x16x32(acc, a, b) \
  asm("v_mfma_f32_16x16x32_bf16 %0, %1, %2, %0" : "+v"(acc) : "v"(a), "v"(b))

#define GLD16(g, l) \
  __builtin_amdgcn_global_load_lds((const __attribute__((address_space(1))) void*)(g), \
                                   (__attribute__((address_space(3))) void*)(l), 16, 0, 0)

// ---------------- router: logits, top-2 softmax, expert lists, x->bf16 ----------------
__global__ __launch_bounds__(256) void router_kernel(
    const float* __restrict__ x, const float* __restrict__ wr,
    int* __restrict__ cnt, int* __restrict__ tokL, float* __restrict__ wgtL,
    unsigned short* __restrict__ xb) {
  __shared__ float rw[NEXP * H_DIM];    // 32 KB
  int tid = threadIdx.x;
#pragma unroll
  for (int it = 0; it < 8; ++it) {
    int i4 = it * 256 + tid;
    ((float4*)rw)[i4] = ((const float4*)wr)[i4];
  }
  __syncthreads();
  int wid = tid >> 6, lane = tid & 63;
  int t = blockIdx.x * 4 + wid;         // one wave per token
  float a[NEXP];
#pragma unroll
  for (int e = 0; e < NEXP; ++e) a[e] = 0.f;
#pragma unroll
  for (int hc = 0; hc < 4; ++hc) {
    int h = hc * 256 + lane * 4;
    float4 xv = *(const float4*)(x + (size_t)t * H_DIM + h);
    ushort4 o;
    o.x = f2bf(xv.x); o.y = f2bf(xv.y); o.z = f2bf(xv.z); o.w = f2bf(xv.w);
    *(ushort4*)(xb + (size_t)t * H_DIM + h) = o;
#pragma unroll
    for (int e = 0; e < NEXP; ++e) {
      float4 w4 = *(const float4*)(&rw[e * H_DIM + h]);
      a[e] += xv.x * w4.x + xv.y * w4.y + xv.z * w4.z + xv.w * w4.w;
    }
  }
#pragma unroll
  for (int e = 0; e < NEXP; ++e) {
    float v = a[e];
    for (int off = 32; off > 0; off >>= 1) v += __shfl_xor(v, off, 64);
    a[e] = v;
  }
  if (lane == 0) {
    int e1 = 0; float l1 = a[0];
#pragma unroll
    for (int e = 1; e < NEXP; ++e) if (a[e] > l1) { l1 = a[e]; e1 = e; }
    int e2 = -1; float l2 = -3.4e38f;
#pragma unroll
    for (int e = 0; e < NEXP; ++e) if (e != e1 && a[e] > l2) { l2 = a[e]; e2 = e; }
    float q = expf(l2 - l1);
    float w1 = 1.f / (1.f + q);
    float w2 = q * w1;
    int p1 = atomicAdd(&cnt[e1], 1);
    tokL[e1 * CAP + p1] = t; wgtL[e1 * CAP + p1] = w1;
    int p2 = atomicAdd(&cnt[e2], 1);
    tokL[e2 * CAP + p2] = t; wgtL[e2 * CAP + p2] = w2;
  }
}

__global__ void scan_kernel(const int* __restrict__ cnt, int* __restrict__ offs) {
  if (threadIdx.x == 0) {
    int s = 0;
    for (int e = 0; e < NEXP; ++e) { offs[e] = s; s += cnt[e]; }
  }
}

// ---------------- fused gate+up transpose: [8][1024][2816] f32 -> [8][2816][1024] bf16 x2 ----------------
__global__ __launch_bounds__(256) void transposeGU_kernel(
    const float* __restrict__ s1, const float* __restrict__ s2,
    unsigned short* __restrict__ d1, unsigned short* __restrict__ d2) {
  __shared__ float tile[64][65];
  int z = blockIdx.z;
  int m = z & 7;
  const float* src = (z < 8) ? s1 : s2;
  unsigned short* dst = (z < 8) ? d1 : d2;
  const int R = H_DIM, C = I_DIM;
  int r0 = blockIdx.y * 64, c0 = blockIdx.x * 64;
  const float* s = src + (size_t)m * R * C;
  unsigned short* d = dst + (size_t)m * R * C;
  int tid = threadIdx.x;
#pragma unroll
  for (int it = 0; it < 4; ++it) {
    int id4 = it * 256 + tid;
    int r = id4 >> 4, c4 = (id4 & 15) * 4;
    float4 v = *(const float4*)(s + (size_t)(r0 + r) * C + c0 + c4);
    tile[r][c4] = v.x; tile[r][c4 + 1] = v.y; tile[r][c4 + 2] = v.z; tile[r][c4 + 3] = v.w;
  }
  __syncthreads();
#pragma unroll
  for (int it = 0; it < 4; ++it) {
    int qd = it * 256 + tid;
    int c = qd >> 4, rq = (qd & 15) * 4;
    ushort4 o;
    o.x = f2bf(tile[rq][c]);     o.y = f2bf(tile[rq + 1][c]);
    o.z = f2bf(tile[rq + 2][c]); o.w = f2bf(tile[rq + 3][c]);
    *(ushort4*)(d + (size_t)(c0 + c) * R + r0 + rq) = o;
  }
}

// ---------------- generic transpose (for w_down) ----------------
__global__ __launch_bounds__(256) void transpose_kernel(
    const float* __restrict__ src, unsigned short* __restrict__ dst, int R, int C) {
  __shared__ float tile[64][65];
  int m = blockIdx.z;
  int r0 = blockIdx.y * 64, c0 = blockIdx.x * 64;
  const float* s = src + (size_t)m * R * C;
  unsigned short* d = dst + (size_t)m * R * C;
  int tid = threadIdx.x;
#pragma unroll
  for (int it = 0; it < 4; ++it) {
    int id4 = it * 256 + tid;
    int r = id4 >> 4, c4 = (id4 & 15) * 4;
    float4 v = *(const float4*)(s + (size_t)(r0 + r) * C + c0 + c4);
    tile[r][c4] = v.x; tile[r][c4 + 1] = v.y; tile[r][c4 + 2] = v.z; tile[r][c4 + 3] = v.w;
  }
  __syncthreads();
#pragma unroll
  for (int it = 0; it < 4; ++it) {
    int qd = it * 256 + tid;
    int c = qd >> 4, rq = (qd & 15) * 4;
    ushort4 o;
    o.x = f2bf(tile[rq][c]);     o.y = f2bf(tile[rq + 1][c]);
    o.z = f2bf(tile[rq + 2][c]); o.w = f2bf(tile[rq + 3][c]);
    *(ushort4*)(d + (size_t)(c0 + c) * R + r0 + rq) = o;
  }
}

// ---------------- gate+up fused grouped GEMM + silu*mul -> h (bf16) ----------------
// R2-exact structure. LDS linear [128][64] bf16; physical (row,c16) holds logical
// (row, c16^(row&7)); staged via GLD16 with pre-swizzled global source col.
__global__ __launch_bounds__(256) void gateup_kernel(
    const unsigned short* __restrict__ xb,
    const unsigned short* __restrict__ wgT,   // [E][I][H] bf16
    const unsigned short* __restrict__ wuT,
    const int* __restrict__ cnt, const int* __restrict__ offs,
    const int* __restrict__ tokL,
    unsigned short* __restrict__ hbuf) {
  int e = blockIdx.z;
  int cnt_e = cnt[e];
  int m0 = blockIdx.y * 128;
  if (m0 >= cnt_e) return;
  int n0 = blockIdx.x * 128;
  int rcnt = cnt_e - m0; if (rcnt > 128) rcnt = 128;

  __shared__ unsigned short As[128 * 64], Gs[128 * 64], Us[128 * 64];  // 48 KB
  __shared__ int trow[128];
  int tid = threadIdx.x;
  if (tid < 128) trow[tid] = tokL[e * CAP + m0 + ((tid < rcnt) ? tid : 0)];
  __syncthreads();

  int lane = tid & 63, wid = tid >> 6;
  int lr = lane >> 3;
  int csrc = ((lane & 7) ^ lr) * 8;          // pre-swizzled source col (shorts)

  const unsigned short* baseA[4];
  const unsigned short* baseG[4];
  const unsigned short* baseU[4];
  int ldso[4];
#pragma unroll
  for (int i = 0; i < 4; ++i) {
    int chunk = i * 4 + wid;
    int row = chunk * 8 + lr;
    baseA[i] = xb + (size_t)trow[row] * H_DIM + csrc;
    size_t wrow = ((size_t)e * I_DIM + n0 + row) * H_DIM + csrc;
    baseG[i] = wgT + wrow;
    baseU[i] = wuT + wrow;
    ldso[i] = chunk * 512;
  }

  int wr = wid >> 1, wc = wid & 1;
  int fr = lane & 15, fg = lane >> 4;
  int fsw = fr & 7;

  f32x4 accg[4][4], accu[4][4];
#pragma unroll
  for (int m = 0; m < 4; ++m)
#pragma unroll
    for (int n = 0; n < 4; ++n) { accg[m][n] = (f32x4)0.f; accu[m][n] = (f32x4)0.f; }

  for (int ks = 0; ks < H_DIM / 64; ++ks) {
    int k0 = ks * 64;
#pragma unroll
    for (int i = 0; i < 4; ++i) {
      GLD16(baseA[i] + k0, As + ldso[i]);
      GLD16(baseG[i] + k0, Gs + ldso[i]);
      GLD16(baseU[i] + k0, Us + ldso[i]);
    }
    __syncthreads();
#pragma unroll
    for (int kk = 0; kk < 2; ++kk) {
      int cb = ((kk * 4 + fg) ^ fsw) * 8;
      bf16x8 am[4], bg[4], bu[4];
#pragma unroll
      for (int m = 0; m < 4; ++m)
        am[m] = *(const bf16x8*)(As + (wr * 64 + m * 16 + fr) * 64 + cb);
#pragma unroll
      for (int n = 0; n < 4; ++n) {
        bg[n] = *(const bf16x8*)(Gs + (wc * 64 + n * 16 + fr) * 64 + cb);
        bu[n] = *(const bf16x8*)(Us + (wc * 64 + n * 16 + fr) * 64 + cb);
      }
#pragma unroll
      for (int m = 0; m < 4; ++m)
#pragma unroll
        for (int n = 0; n < 4; ++n) {
          MFMA16x16x32(accg[m][n], am[m], bg[n]);
          MFMA16x16x32(accu[m][n], am[m], bu[n]);
        }
    }
    __syncthreads();
  }
  int hb = offs[e];
#pragma unroll
  for (int m = 0; m < 4; ++m)
#pragma unroll
    for (int q = 0; q < 4; ++q) {
      int row = wr * 64 + m * 16 + fg * 4 + q;
      if (row < rcnt) {
        size_t rbase = (size_t)(hb + m0 + row) * I_DIM + n0 + wc * 64;
#pragma unroll
        for (int n = 0; n < 4; ++n) {
          float g = accg[m][n][q], u = accu[m][n][q];
          hbuf[rbase + n * 16 + fr] = f2bf(g / (1.f + expf(-g)) * u);
        }
      }
    }
}

// ---------------- down grouped GEMM, split-K x2, weighted atomic scatter-add ----------------
__global__ __launch_bounds__(256) void down_kernel(
    const unsigned short* __restrict__ hbuf,
    const unsigned short* __restrict__ wdT,   // [E][H][I] bf16
    const int* __restrict__ cnt, const int* __restrict__ offs,
    const int* __restrict__ tokL, const float* __restrict__ wgtL,
    float* __restrict__ out) {
  int e = blockIdx.z;
  int cnt_e = cnt[e];
  int m0 = blockIdx.y * 128;
  if (m0 >= cnt_e) return;
  int n0 = (blockIdx.x >> 1) * 128;
  int kpart = blockIdx.x & 1;                 // 0: ks 0..21, 1: ks 22..43
  int rcnt = cnt_e - m0; if (rcnt > 128) rcnt = 128;
  int hb = offs[e];

  __shared__ unsigned short As[128 * 64], Bs[128 * 64];   // 32 KB
  int tid = threadIdx.x, lane = tid & 63, wid = tid >> 6;
  int lr = lane >> 3;
  int csrc = ((lane & 7) ^ lr) * 8;

  const unsigned short* baseA[4];
  const unsigned short* baseB[4];
  int ldso[4];
#pragma unroll
  for (int i = 0; i < 4; ++i) {
    int chunk = i * 4 + wid;
    int row = chunk * 8 + lr;
    int rowc = (row < rcnt) ? row : (rcnt - 1);           // clamp: stay in-expert
    baseA[i] = hbuf + (size_t)(hb + m0 + rowc) * I_DIM + csrc;
    baseB[i] = wdT + ((size_t)e * H_DIM + n0 + row) * I_DIM + csrc;
    ldso[i] = chunk * 512;
  }

  int wr = wid >> 1, wc = wid & 1, fr = lane & 15, fg = lane >> 4;
  int fsw = fr & 7;

  f32x4 acc[4][4];
#pragma unroll
  for (int m = 0; m < 4; ++m)
#pragma unroll
    for (int n = 0; n < 4; ++n) acc[m][n] = (f32x4)0.f;

  int ks0 = kpart * 22;
  for (int ks = ks0; ks < ks0 + 22; ++ks) {   // 22 of 44 K-steps
    int k0 = ks * 64;
#pragma unroll
    for (int i = 0; i < 4; ++i) {
      GLD16(baseA[i] + k0, As + ldso[i]);
      GLD16(baseB[i] + k0, Bs + ldso[i]);
    }
    __syncthreads();
#pragma unroll
    for (int kk = 0; kk < 2; ++kk) {
      int cb = ((kk * 4 + fg) ^ fsw) * 8;
      bf16x8 am[4], bn[4];
#pragma unroll
      for (int m = 0; m < 4; ++m)
        am[m] = *(const bf16x8*)(As + (wr * 64 + m * 16 + fr) * 64 + cb);
#pragma unroll
      for (int n = 0; n < 4; ++n)
        bn[n] = *(const bf16x8*)(Bs + (wc * 64 + n * 16 + fr) * 64 + cb);
#pragma unroll
      for (int m = 0; m < 4; ++m)
#pragma unroll
        for (int n = 0; n < 4; ++n)
          MFMA16x16x32(acc[m][n], am[m], bn[n]);
    }
    __syncthreads();
  }
#pragma unroll
  for (int m = 0; m < 4; ++m)
#pragma unroll
    for (int q = 0; q < 4; ++q) {
      int row = wr * 64 + m * 16 + fg * 4 + q;
      if (row < rcnt) {
        float w = wgtL[e * CAP + m0 + row];
        int t = tokL[e * CAP + m0 + row];
        float* obase = out + (size_t)t * H_DIM + n0 + wc * 64;
#pragma unroll
        for (int n = 0; n < 4; ++n)
          atomicAdd(obase + n * 16 + fr, w * acc[m][n][q]);
      }
    }
}

extern "C" void kernel_launch(void* const* d_in, const int* in_sizes, int n_in,
                              void* d_out, int out_size, void* d_ws, size_t ws_size,
                              hipStream_t stream) {
  const float* x   = (const float*)d_in[0];
  const float* wr  = (const float*)d_in[1];
  const float* wg  = (const float*)d_in[2];
  const float* wu  = (const float*)d_in[3];
  const float* wd  = (const float*)d_in[4];
  float* out = (float*)d_out;

  char* ws = (char*)d_ws;
  int*   cnt  = (int*)ws;
  int*   offs = (int*)(ws + 64);
  int*   tokL = (int*)(ws + 1024);
  float* wgtL = (float*)(ws + 1024 + (size_t)NEXP * CAP * 4);
  unsigned short* xb  = (unsigned short*)(ws + (1u << 20));
  unsigned short* wgT = (unsigned short*)(ws + (1u << 20) + (size_t)T_TOK * H_DIM * 2);
  unsigned short* wuT = wgT + (size_t)NEXP * I_DIM * H_DIM;
  unsigned short* wdT = wuT + (size_t)NEXP * I_DIM * H_DIM;
  unsigned short* hbuf = wdT + (size_t)NEXP * H_DIM * I_DIM;

  hipMemsetAsync(ws, 0, 64, stream);                        // counts
  hipMemsetAsync(d_out, 0, (size_t)out_size * 4, stream);   // atomics accumulate

  router_kernel<<<T_TOK / 4, 256, 0, stream>>>(x, wr, cnt, tokL, wgtL, xb);
  scan_kernel<<<1, 64, 0, stream>>>(cnt, offs);

  transposeGU_kernel<<<dim3(I_DIM / 64, H_DIM / 64, 16), 256, 0, stream>>>(wg, wu, wgT, wuT);
  transpose_kernel<<<dim3(H_DIM / 64, I_DIM / 64, NEXP), 256, 0, stream>>>(wd, wdT, I_DIM, H_DIM);

  gateup_kernel<<<dim3(I_DIM / 128, CAP / 128, NEXP), 256, 0, stream>>>(
      xb, wgT, wuT, cnt, offs, tokL, hbuf);
  down_kernel<<<dim3(2 * (H_DIM / 128), CAP / 128, NEXP), 256, 0, stream>>>(
      hbuf, wdT, cnt, offs, tokL, wgtL, out);
}